// Round 1
// baseline (2276.150 us; speedup 1.0000x reference)
//
#include <hip/hip_runtime.h>
#include <math.h>

#define EMBED 512
#define NHEAD 8
#define DHEAD 64
#define SEQ   8192
#define EPS   1e-6f

// ---------------------------------------------------------------------------
// GEMM: C[M,N] = act(A[M,512] * W[N,512]^T + bias[N]) , N = 512.
// fp32 vector-ALU GEMM. BM=BN=128, BK=16, 256 threads, 8x8 microtile/thread.
// LDS tiles stored transposed [k][m] so fragment reads are contiguous b128.
// ---------------------------------------------------------------------------
template <bool ACT>
__global__ __launch_bounds__(256) void proj_kernel(
    const float* __restrict__ A, const float* __restrict__ W,
    const float* __restrict__ bias, float* __restrict__ C, int M) {
  const int K = EMBED;
  __shared__ float As[16][132];  // [k][m], pad 132 (2-way max on transpose store)
  __shared__ float Bs[16][132];  // [k][n]

  const int t = threadIdx.x;
  const int bm = blockIdx.x;  // M/128
  const int bn = blockIdx.y;  // 512/128 = 4
  const int m0 = bm * 128;
  const int n0 = bn * 128;
  const int ty = t >> 4;   // 0..15 -> m = ty*8 + i
  const int tx = t & 15;   // 0..15 -> n = tx*8 + j

  float acc[8][8];
#pragma unroll
  for (int i = 0; i < 8; ++i)
#pragma unroll
    for (int j = 0; j < 8; ++j) acc[i][j] = 0.f;

  for (int kt = 0; kt < K / 16; ++kt) {
    const int kb = kt * 16;
    // stage: 128 rows x 16 k-cols = 2048 floats each for A and B.
    // 256 threads x 2 float4 each. flat f in [0,512): row=f/4, cg=f%4.
#pragma unroll
    for (int i = 0; i < 2; ++i) {
      const int f = t + i * 256;
      const int row = f >> 2;
      const int cg = (f & 3) * 4;
      float4 av = *(const float4*)&A[(size_t)(m0 + row) * K + kb + cg];
      float4 bv = *(const float4*)&W[(size_t)(n0 + row) * K + kb + cg];
      As[cg + 0][row] = av.x; As[cg + 1][row] = av.y;
      As[cg + 2][row] = av.z; As[cg + 3][row] = av.w;
      Bs[cg + 0][row] = bv.x; Bs[cg + 1][row] = bv.y;
      Bs[cg + 2][row] = bv.z; Bs[cg + 3][row] = bv.w;
    }
    __syncthreads();
#pragma unroll
    for (int kk = 0; kk < 16; ++kk) {
      float4 a0 = *(float4*)&As[kk][ty * 8];
      float4 a1 = *(float4*)&As[kk][ty * 8 + 4];
      float4 b0 = *(float4*)&Bs[kk][tx * 8];
      float4 b1 = *(float4*)&Bs[kk][tx * 8 + 4];
      float a[8] = {a0.x, a0.y, a0.z, a0.w, a1.x, a1.y, a1.z, a1.w};
      float b[8] = {b0.x, b0.y, b0.z, b0.w, b1.x, b1.y, b1.z, b1.w};
#pragma unroll
      for (int i = 0; i < 8; ++i)
#pragma unroll
        for (int j = 0; j < 8; ++j) acc[i][j] = fmaf(a[i], b[j], acc[i][j]);
    }
    __syncthreads();
  }

  // epilogue: bias (+ elu(x)+1 if ACT), float4 stores
#pragma unroll
  for (int i = 0; i < 8; ++i) {
    float out[8];
#pragma unroll
    for (int j = 0; j < 8; ++j) {
      float v = acc[i][j] + bias[n0 + tx * 8 + j];
      if (ACT) v = (v > 0.f) ? (v + 1.f) : __expf(v);
      out[j] = v;
    }
    float* cp = &C[(size_t)(m0 + ty * 8 + i) * EMBED + n0 + tx * 8];
    *(float4*)cp = make_float4(out[0], out[1], out[2], out[3]);
    *(float4*)(cp + 4) = make_float4(out[4], out[5], out[6], out[7]);
  }
}

// ---------------------------------------------------------------------------
// KV[nh][m][d] += sum_s V[s][m] * K[s][d] ;  Ksum[nh][d] += sum_s K[s][d]
// grid (64, 32): block handles 256 rows of one (n,h); split-K via atomics.
// ---------------------------------------------------------------------------
__global__ __launch_bounds__(256) void kv_kernel(
    const float* __restrict__ Kf, const float* __restrict__ Vf,
    float* __restrict__ KV, float* __restrict__ Ksum) {
  const int nh = blockIdx.x;
  const int n = nh >> 3, h = nh & 7;
  const int sbeg = blockIdx.y * 256;
  __shared__ float Ks[32][64];
  __shared__ float Vs[32][64];
  const int t = threadIdx.x;
  const int ty = t >> 4, tx = t & 15;  // m = ty*4+i, d = tx*4+j
  float acc[4][4] = {};
  float ks[4] = {};

  for (int s0 = 0; s0 < 256; s0 += 32) {
#pragma unroll
    for (int i = 0; i < 2; ++i) {
      const int f = t + i * 256;       // 0..511 = 32 rows x 16 float4
      const int r = f >> 4, cg = (f & 15) * 4;
      const size_t g = ((size_t)(n * SEQ + sbeg + s0 + r)) * EMBED + h * 64 + cg;
      *(float4*)&Ks[r][cg] = *(const float4*)&Kf[g];
      *(float4*)&Vs[r][cg] = *(const float4*)&Vf[g];
    }
    __syncthreads();
#pragma unroll 8
    for (int s = 0; s < 32; ++s) {
      float4 vv = *(float4*)&Vs[s][ty * 4];
      float4 kk = *(float4*)&Ks[s][tx * 4];
      float v4[4] = {vv.x, vv.y, vv.z, vv.w};
      float k4[4] = {kk.x, kk.y, kk.z, kk.w};
#pragma unroll
      for (int i = 0; i < 4; ++i)
#pragma unroll
        for (int j = 0; j < 4; ++j) acc[i][j] = fmaf(v4[i], k4[j], acc[i][j]);
      if (ty == 0) {
#pragma unroll
        for (int j = 0; j < 4; ++j) ks[j] += k4[j];
      }
    }
    __syncthreads();
  }
  float* kvb = &KV[(size_t)nh * 4096];
#pragma unroll
  for (int i = 0; i < 4; ++i)
#pragma unroll
    for (int j = 0; j < 4; ++j)
      atomicAdd(&kvb[(ty * 4 + i) * 64 + tx * 4 + j], acc[i][j]);
  if (ty == 0) {
#pragma unroll
    for (int j = 0; j < 4; ++j) atomicAdd(&Ksum[nh * 64 + tx * 4 + j], ks[j]);
  }
}

// ---------------------------------------------------------------------------
// V[l, h*64+m] = Z(l) * sum_d Q[l,d] * KV[m,d],  Z = 1/(dot(Q_l, Ksum)+eps)
// grid (64, 32), block 256 = 4 waves; lane owns output column m.
// ---------------------------------------------------------------------------
__global__ __launch_bounds__(256) void stage3_kernel(
    const float* __restrict__ Qf, const float* __restrict__ KV,
    const float* __restrict__ Ksum, float* __restrict__ Vout) {
  const int nh = blockIdx.x;
  const int n = nh >> 3, h = nh & 7;
  __shared__ float KVs[64][65];
  __shared__ float Qs[64][65];
  __shared__ float Ksums[64];
  __shared__ float zs[64];
  const int t = threadIdx.x;

  // load KV tile (4096 floats) + Ksum
#pragma unroll
  for (int i = 0; i < 16; ++i) {
    const int idx = t + i * 256;
    KVs[idx >> 6][idx & 63] = KV[(size_t)nh * 4096 + idx];
  }
  if (t < 64) Ksums[t] = Ksum[nh * 64 + t];
  __syncthreads();

  const int w = t >> 6, lane = t & 63;
  for (int c = 0; c < 4; ++c) {
    const int l0 = blockIdx.y * 256 + c * 64;
    // stage 64 Q rows (head slice)
#pragma unroll
    for (int i = 0; i < 16; ++i) {
      const int idx = t + i * 256;
      const int r = idx >> 6, d = idx & 63;
      Qs[r][d] = Qf[(size_t)(n * SEQ + l0 + r) * EMBED + h * 64 + d];
    }
    __syncthreads();
    if (t < 64) {  // z for row t
      float sum = 0.f;
#pragma unroll
      for (int d = 0; d < 64; ++d) sum = fmaf(Qs[t][d], Ksums[d], sum);
      zs[t] = 1.f / (sum + EPS);
    }
    __syncthreads();
    // each wave: 16 rows; lane = output column m
#pragma unroll 1
    for (int rr = 0; rr < 16; ++rr) {
      const int l = w * 16 + rr;
      const float z = zs[l];
      float sum = 0.f;
#pragma unroll
      for (int d = 0; d < 64; ++d) sum = fmaf(Qs[l][d], KVs[lane][d], sum);
      Vout[(size_t)(n * SEQ + l0 + l) * EMBED + h * 64 + lane] = z * sum;
    }
    __syncthreads();
  }
}

// ---------------------------------------------------------------------------
extern "C" void kernel_launch(void* const* d_in, const int* in_sizes, int n_in,
                              void* d_out, int out_size, void* d_ws,
                              size_t ws_size, hipStream_t stream) {
  const float* query = (const float*)d_in[0];
  const float* key   = (const float*)d_in[1];
  const float* value = (const float*)d_in[2];
  const float* Wq = (const float*)d_in[3];
  const float* bq = (const float*)d_in[4];
  const float* Wk = (const float*)d_in[5];
  const float* bk = (const float*)d_in[6];
  const float* Wv = (const float*)d_in[7];
  const float* bv = (const float*)d_in[8];
  const float* Wo = (const float*)d_in[9];
  const float* bo = (const float*)d_in[10];
  float* out = (float*)d_out;

  const int M = in_sizes[0] / EMBED;  // 65536
  const size_t big = (size_t)M * EMBED * sizeof(float);  // 134 MB

  char* ws = (char*)d_ws;
  float* Qb = (float*)(ws);                // feature-mapped Q
  float* Kb = (float*)(ws + big);          // feature-mapped K; reused as Vout
  float* Vb = (float*)(ws + 2 * big);      // projected v
  float* KV = (float*)(ws + 3 * big);      // 64*64*64 floats = 1 MB
  float* Ksum = (float*)(ws + 3 * big + 64 * 64 * 64 * sizeof(float));  // 16 KB

  hipMemsetAsync(KV, 0, (64 * 64 * 64 + 64 * 64) * sizeof(float), stream);

  dim3 gproj(M / 128, EMBED / 128);
  proj_kernel<true><<<gproj, 256, 0, stream>>>(query, Wq, bq, Qb, M);
  proj_kernel<true><<<gproj, 256, 0, stream>>>(key, Wk, bk, Kb, M);
  proj_kernel<false><<<gproj, 256, 0, stream>>>(value, Wv, bv, Vb, M);

  kv_kernel<<<dim3(64, 32), 256, 0, stream>>>(Kb, Vb, KV, Ksum);

  float* Vout = Kb;  // K no longer needed
  stage3_kernel<<<dim3(64, 32), 256, 0, stream>>>(Qb, KV, Ksum, Vout);

  proj_kernel<false><<<gproj, 256, 0, stream>>>(Vout, Wo, bo, out, M);
}

// Round 2
// 1315.141 us; speedup vs baseline: 1.7307x; 1.7307x over previous
//
#include <hip/hip_runtime.h>
#include <math.h>

#define EMBED 512
#define SEQ   8192
#define EPS   1e-6f

typedef __attribute__((ext_vector_type(8))) short bf16x8;
typedef __attribute__((ext_vector_type(4))) float f32x4;
typedef unsigned short ushort_t;
typedef unsigned int uint_t;

__device__ __forceinline__ ushort_t f2bf(float x) {  // RNE float->bf16
  uint_t b = __float_as_uint(x);
  b += 0x7fff + ((b >> 16) & 1);
  return (ushort_t)(b >> 16);
}
__device__ __forceinline__ float bf2f(ushort_t u) {
  return __uint_as_float(((uint_t)u) << 16);
}
__device__ __forceinline__ float bfhi(uint_t packed) {  // high bf16 of a uint
  return __uint_as_float(packed & 0xffff0000u);
}
__device__ __forceinline__ float bflo(uint_t packed) {  // low bf16 of a uint
  return __uint_as_float(packed << 16);
}

// ---------------------------------------------------------------------------
// split fp32 x -> bf16 hi + bf16 lo  (x ~= hi + lo, error <= 2^-18 |x|)
// ---------------------------------------------------------------------------
__global__ void convert_split(const float* __restrict__ x,
                              ushort_t* __restrict__ h,
                              ushort_t* __restrict__ l, int n4) {
  const int stride = gridDim.x * blockDim.x;
  for (int i = blockIdx.x * blockDim.x + threadIdx.x; i < n4; i += stride) {
    float4 v = ((const float4*)x)[i];
    ushort_t h0 = f2bf(v.x), h1 = f2bf(v.y), h2 = f2bf(v.z), h3 = f2bf(v.w);
    ushort_t l0 = f2bf(v.x - bf2f(h0)), l1 = f2bf(v.y - bf2f(h1));
    ushort_t l2 = f2bf(v.z - bf2f(h2)), l3 = f2bf(v.w - bf2f(h3));
    uint2 hv, lv;
    hv.x = (uint_t)h0 | ((uint_t)h1 << 16); hv.y = (uint_t)h2 | ((uint_t)h3 << 16);
    lv.x = (uint_t)l0 | ((uint_t)l1 << 16); lv.y = (uint_t)l2 | ((uint_t)l3 << 16);
    ((uint2*)h)[i] = hv; ((uint2*)l)[i] = lv;
  }
}

// ---------------------------------------------------------------------------
// C[M,512] = act(A * W^T + bias).  A given as bf16 hi/lo pair (fp32-split),
// W likewise. 3-MFMA split: AhWh + AhWl + AlWh. 128x128 tile, BK=32,
// 256 thr (4 waves 2x2, 64x64/wave), global_load_lds(16B) staging with
// chunk-XOR swizzle (p = c ^ ((r>>1)&3)) applied via source address so
// ds_read_b128 frag reads are 2-way (free) on banks.
// ---------------------------------------------------------------------------
template <bool ACT, bool SPLIT_OUT>
__global__ __launch_bounds__(256) void gemm_split(
    const ushort_t* __restrict__ Ah, const ushort_t* __restrict__ Al,
    const ushort_t* __restrict__ Bh, const ushort_t* __restrict__ Bl,
    const float* __restrict__ bias,
    ushort_t* __restrict__ Ch, ushort_t* __restrict__ Cl,
    float* __restrict__ Cf, int M) {
  __shared__ __align__(16) ushort_t lAh[128 * 32];
  __shared__ __align__(16) ushort_t lAl[128 * 32];
  __shared__ __align__(16) ushort_t lBh[128 * 32];
  __shared__ __align__(16) ushort_t lBl[128 * 32];

  const int t = threadIdx.x;
  const int m0 = blockIdx.x * 128;
  const int n0 = blockIdx.y * 128;
  const int w = t >> 6, lane = t & 63;
  const int wr = w >> 1, wc = w & 1;
  const int fl = lane & 15, kb = lane >> 4;  // frag lane row/col, k-block

  f32x4 acc[4][4];
#pragma unroll
  for (int mi = 0; mi < 4; ++mi)
#pragma unroll
    for (int ni = 0; ni < 4; ++ni) acc[mi][ni] = (f32x4){0.f, 0.f, 0.f, 0.f};

  for (int kt = 0; kt < EMBED / 32; ++kt) {
#pragma unroll
    for (int j = 0; j < 2; ++j) {
      const int i = t + j * 256;          // 16B-chunk id within tile
      const int r = i >> 2, p = i & 3;    // row, physical chunk
      const int c = p ^ ((r >> 1) & 3);   // logical chunk (involution)
      const size_t ga = (size_t)(m0 + r) * EMBED + kt * 32 + c * 8;
      const size_t gb = (size_t)(n0 + r) * EMBED + kt * 32 + c * 8;
      __builtin_amdgcn_global_load_lds(
          (const __attribute__((address_space(1))) void*)(const void*)&Ah[ga],
          (__attribute__((address_space(3))) void*)(void*)&lAh[(size_t)i * 8], 16, 0, 0);
      __builtin_amdgcn_global_load_lds(
          (const __attribute__((address_space(1))) void*)(const void*)&Al[ga],
          (__attribute__((address_space(3))) void*)(void*)&lAl[(size_t)i * 8], 16, 0, 0);
      __builtin_amdgcn_global_load_lds(
          (const __attribute__((address_space(1))) void*)(const void*)&Bh[gb],
          (__attribute__((address_space(3))) void*)(void*)&lBh[(size_t)i * 8], 16, 0, 0);
      __builtin_amdgcn_global_load_lds(
          (const __attribute__((address_space(1))) void*)(const void*)&Bl[gb],
          (__attribute__((address_space(3))) void*)(void*)&lBl[(size_t)i * 8], 16, 0, 0);
    }
    __syncthreads();

    bf16x8 fah[4], fal[4], fbh[4], fbl[4];
#pragma unroll
    for (int mi = 0; mi < 4; ++mi) {
      const int r = wr * 64 + mi * 16 + fl;
      const int p = kb ^ ((r >> 1) & 3);
      const int off = r * 32 + p * 8;
      fah[mi] = *(const bf16x8*)&lAh[off];
      fal[mi] = *(const bf16x8*)&lAl[off];
    }
#pragma unroll
    for (int ni = 0; ni < 4; ++ni) {
      const int r = wc * 64 + ni * 16 + fl;
      const int p = kb ^ ((r >> 1) & 3);
      const int off = r * 32 + p * 8;
      fbh[ni] = *(const bf16x8*)&lBh[off];
      fbl[ni] = *(const bf16x8*)&lBl[off];
    }
#pragma unroll
    for (int mi = 0; mi < 4; ++mi)
#pragma unroll
      for (int ni = 0; ni < 4; ++ni) {
        acc[mi][ni] = __builtin_amdgcn_mfma_f32_16x16x32_bf16(fah[mi], fbh[ni], acc[mi][ni], 0, 0, 0);
        acc[mi][ni] = __builtin_amdgcn_mfma_f32_16x16x32_bf16(fah[mi], fbl[ni], acc[mi][ni], 0, 0, 0);
        acc[mi][ni] = __builtin_amdgcn_mfma_f32_16x16x32_bf16(fal[mi], fbh[ni], acc[mi][ni], 0, 0, 0);
      }
    __syncthreads();
  }

  // epilogue: C/D layout col = lane&15, row = (lane>>4)*4 + reg  [m89/m91]
  const int rq = lane >> 4;
#pragma unroll
  for (int mi = 0; mi < 4; ++mi)
#pragma unroll
    for (int ni = 0; ni < 4; ++ni) {
      const int col = n0 + wc * 64 + ni * 16 + fl;
      const float bv = bias[col];
#pragma unroll
      for (int q = 0; q < 4; ++q) {
        const int row = m0 + wr * 64 + mi * 16 + rq * 4 + q;
        float v = acc[mi][ni][q] + bv;
        if (ACT) v = (v > 0.f) ? (v + 1.f) : __expf(v);
        const size_t g = (size_t)row * EMBED + col;
        if (SPLIT_OUT) {
          const ushort_t hh = f2bf(v);
          Ch[g] = hh;
          Cl[g] = f2bf(v - bf2f(hh));
        } else {
          Cf[g] = v;
        }
      }
    }
}

// ---------------------------------------------------------------------------
// KV[nh][m][d] += sum_s V[s][m]*K[s][d];  Ksum[nh][d] += sum_s K[s][d]
// K,V given as bf16 hi/lo pairs. grid (64, 32), split-K atomics.
// ---------------------------------------------------------------------------
__global__ __launch_bounds__(256) void kv_kernel(
    const ushort_t* __restrict__ Kh, const ushort_t* __restrict__ Kl,
    const ushort_t* __restrict__ Vh, const ushort_t* __restrict__ Vl,
    float* __restrict__ KV, float* __restrict__ Ksum) {
  const int nh = blockIdx.x;
  const int n = nh >> 3, h = nh & 7;
  const int sbeg = blockIdx.y * 256;
  __shared__ float Ks[32][64];
  __shared__ float Vs[32][64];
  const int t = threadIdx.x;
  const int ty = t >> 4, tx = t & 15;
  float acc[4][4] = {};
  float ks[4] = {};

  for (int s0 = 0; s0 < 256; s0 += 32) {
#pragma unroll
    for (int i = 0; i < 2; ++i) {
      const int f = t + i * 256;  // 32 rows x 16 groups-of-4
      const int r = f >> 4, cg = (f & 15) * 4;
      const size_t g = ((size_t)(n * SEQ + sbeg + s0 + r)) * EMBED + h * 64 + cg;
      uint2 kh = *(const uint2*)&Kh[g], kl = *(const uint2*)&Kl[g];
      uint2 vh = *(const uint2*)&Vh[g], vl = *(const uint2*)&Vl[g];
      Ks[r][cg + 0] = bflo(kh.x) + bflo(kl.x);
      Ks[r][cg + 1] = bfhi(kh.x) + bfhi(kl.x);
      Ks[r][cg + 2] = bflo(kh.y) + bflo(kl.y);
      Ks[r][cg + 3] = bfhi(kh.y) + bfhi(kl.y);
      Vs[r][cg + 0] = bflo(vh.x) + bflo(vl.x);
      Vs[r][cg + 1] = bfhi(vh.x) + bfhi(vl.x);
      Vs[r][cg + 2] = bflo(vh.y) + bflo(vl.y);
      Vs[r][cg + 3] = bfhi(vh.y) + bfhi(vl.y);
    }
    __syncthreads();
#pragma unroll 8
    for (int s = 0; s < 32; ++s) {
      float4 vv = *(float4*)&Vs[s][ty * 4];
      float4 kk = *(float4*)&Ks[s][tx * 4];
      float v4[4] = {vv.x, vv.y, vv.z, vv.w};
      float k4[4] = {kk.x, kk.y, kk.z, kk.w};
#pragma unroll
      for (int i = 0; i < 4; ++i)
#pragma unroll
        for (int j = 0; j < 4; ++j) acc[i][j] = fmaf(v4[i], k4[j], acc[i][j]);
      if (ty == 0) {
#pragma unroll
        for (int j = 0; j < 4; ++j) ks[j] += k4[j];
      }
    }
    __syncthreads();
  }
  float* kvb = &KV[(size_t)nh * 4096];
#pragma unroll
  for (int i = 0; i < 4; ++i)
#pragma unroll
    for (int j = 0; j < 4; ++j)
      atomicAdd(&kvb[(ty * 4 + i) * 64 + tx * 4 + j], acc[i][j]);
  if (ty == 0) {
#pragma unroll
    for (int j = 0; j < 4; ++j) atomicAdd(&Ksum[nh * 64 + tx * 4 + j], ks[j]);
  }
}

// ---------------------------------------------------------------------------
// Vout[l, h*64+m] = Z(l) * sum_d Q[l,d]*KV[m,d];  Z = 1/(dot(Q_l,Ksum)+eps)
// Q as hi/lo; Vout written as hi/lo.
// ---------------------------------------------------------------------------
__global__ __launch_bounds__(256) void stage3_kernel(
    const ushort_t* __restrict__ Qh, const ushort_t* __restrict__ Ql,
    const float* __restrict__ KV, const float* __restrict__ Ksum,
    ushort_t* __restrict__ VoH, ushort_t* __restrict__ VoL) {
  const int nh = blockIdx.x;
  const int n = nh >> 3, h = nh & 7;
  __shared__ float KVs[64][65];
  __shared__ float Qs[64][65];
  __shared__ float Ksums[64];
  __shared__ float zs[64];
  const int t = threadIdx.x;

#pragma unroll
  for (int i = 0; i < 16; ++i) {
    const int idx = t + i * 256;
    KVs[idx >> 6][idx & 63] = KV[(size_t)nh * 4096 + idx];
  }
  if (t < 64) Ksums[t] = Ksum[nh * 64 + t];
  __syncthreads();

  const int w = t >> 6, lane = t & 63;
  for (int c = 0; c < 4; ++c) {
    const int l0 = blockIdx.y * 256 + c * 64;
#pragma unroll
    for (int i = 0; i < 16; ++i) {
      const int idx = t + i * 256;
      const int r = idx >> 6, d = idx & 63;
      const size_t g = (size_t)(n * SEQ + l0 + r) * EMBED + h * 64 + d;
      Qs[r][d] = bf2f(Qh[g]) + bf2f(Ql[g]);
    }
    __syncthreads();
    if (t < 64) {
      float sum = 0.f;
#pragma unroll
      for (int d = 0; d < 64; ++d) sum = fmaf(Qs[t][d], Ksums[d], sum);
      zs[t] = 1.f / (sum + EPS);
    }
    __syncthreads();
#pragma unroll 1
    for (int rr = 0; rr < 16; ++rr) {
      const int l = w * 16 + rr;
      const float z = zs[l];
      float sum = 0.f;
#pragma unroll
      for (int d = 0; d < 64; ++d) sum = fmaf(Qs[l][d], KVs[lane][d], sum);
      const float v = z * sum;
      const size_t g = (size_t)(n * SEQ + l0 + l) * EMBED + h * 64 + lane;
      const ushort_t hh = f2bf(v);
      VoH[g] = hh;
      VoL[g] = f2bf(v - bf2f(hh));
    }
    __syncthreads();
  }
}

// ---------------------------------------------------------------------------
extern "C" void kernel_launch(void* const* d_in, const int* in_sizes, int n_in,
                              void* d_out, int out_size, void* d_ws,
                              size_t ws_size, hipStream_t stream) {
  const float* query = (const float*)d_in[0];
  const float* key   = (const float*)d_in[1];
  const float* value = (const float*)d_in[2];
  const float* Wq = (const float*)d_in[3];
  const float* bq = (const float*)d_in[4];
  const float* Wk = (const float*)d_in[5];
  const float* bk = (const float*)d_in[6];
  const float* Wv = (const float*)d_in[7];
  const float* bv = (const float*)d_in[8];
  const float* Wo = (const float*)d_in[9];
  const float* bo = (const float*)d_in[10];

  const int M = in_sizes[0] / EMBED;        // 65536
  const size_t ME = (size_t)M * EMBED;      // 33.5M elems

  // ws layout: 3 slots of (hi+lo) bf16 [M][512], then KV, Ksum, W scratch.
  ushort_t* S1h = (ushort_t*)d_ws;  ushort_t* S1l = S1h + ME;
  ushort_t* S2h = S1h + 2 * ME;     ushort_t* S2l = S1h + 3 * ME;
  ushort_t* S3h = S1h + 4 * ME;     ushort_t* S3l = S1h + 5 * ME;
  float* KV   = (float*)(S1h + 6 * ME);          // 64*64*64 floats
  float* Ksum = KV + 64 * 64 * 64;               // 64*64 floats
  ushort_t* Wh = (ushort_t*)(Ksum + 64 * 64);
  ushort_t* Wl = Wh + (size_t)EMBED * EMBED;

  hipMemsetAsync(KV, 0, (64 * 64 * 64 + 64 * 64) * sizeof(float), stream);

  const int n4big = (int)(ME / 4);
  const int n4w = EMBED * EMBED / 4;
  dim3 gg(M / 128, EMBED / 128);

  // Kb = elu(key@Wk^T + bk)+1  -> S2
  convert_split<<<2048, 256, 0, stream>>>(key, S1h, S1l, n4big);
  convert_split<<<256, 256, 0, stream>>>(Wk, Wh, Wl, n4w);
  gemm_split<true, true><<<gg, 256, 0, stream>>>(S1h, S1l, Wh, Wl, bk, S2h, S2l, nullptr, M);

  // Vb = value@Wv^T + bv  -> S3
  convert_split<<<2048, 256, 0, stream>>>(value, S1h, S1l, n4big);
  convert_split<<<256, 256, 0, stream>>>(Wv, Wh, Wl, n4w);
  gemm_split<false, true><<<gg, 256, 0, stream>>>(S1h, S1l, Wh, Wl, bv, S3h, S3l, nullptr, M);

  // KV, Ksum from S2 (K), S3 (v)
  kv_kernel<<<dim3(64, 32), 256, 0, stream>>>(S2h, S2l, S3h, S3l, KV, Ksum);

  // Qb = elu(query@Wq^T + bq)+1 -> S2 (free after kv)
  convert_split<<<2048, 256, 0, stream>>>(query, S1h, S1l, n4big);
  convert_split<<<256, 256, 0, stream>>>(Wq, Wh, Wl, n4w);
  gemm_split<true, true><<<gg, 256, 0, stream>>>(S1h, S1l, Wh, Wl, bq, S2h, S2l, nullptr, M);

  // Vout -> S3 (free after kv)
  stage3_kernel<<<dim3(64, 32), 256, 0, stream>>>(S2h, S2l, KV, Ksum, S3h, S3l);

  // out = Vout@Wo^T + bo (fp32)
  convert_split<<<256, 256, 0, stream>>>(Wo, Wh, Wl, n4w);
  gemm_split<false, false><<<gg, 256, 0, stream>>>(S3h, S3l, Wh, Wl, bo, nullptr, nullptr, (float*)d_out, M);
}

// Round 3
// 1220.069 us; speedup vs baseline: 1.8656x; 1.0779x over previous
//
#include <hip/hip_runtime.h>
#include <math.h>

#define EMBED 512
#define SEQ   8192
#define EPS   1e-6f

typedef __attribute__((ext_vector_type(8))) short bf16x8;
typedef __attribute__((ext_vector_type(4))) float f32x4;
typedef unsigned short ushort_t;
typedef unsigned int uint_t;

__device__ __forceinline__ ushort_t f2bf(float x) {  // RNE float->bf16
  uint_t b = __float_as_uint(x);
  b += 0x7fff + ((b >> 16) & 1);
  return (ushort_t)(b >> 16);
}
__device__ __forceinline__ float bf2f(ushort_t u) {
  return __uint_as_float(((uint_t)u) << 16);
}
__device__ __forceinline__ float bfhi(uint_t packed) {
  return __uint_as_float(packed & 0xffff0000u);
}
__device__ __forceinline__ float bflo(uint_t packed) {
  return __uint_as_float(packed << 16);
}

#define GLL(srcp, dstp)                                                       \
  __builtin_amdgcn_global_load_lds(                                           \
      (const __attribute__((address_space(1))) void*)(const void*)(srcp),     \
      (__attribute__((address_space(3))) void*)(void*)(dstp), 16, 0, 0)

// ---------------------------------------------------------------------------
// split fp32 x -> bf16 hi + bf16 lo  (x ~= hi + lo, error <= 2^-18 |x|)
// ---------------------------------------------------------------------------
__global__ void convert_split(const float* __restrict__ x,
                              ushort_t* __restrict__ h,
                              ushort_t* __restrict__ l, int n4) {
  const int stride = gridDim.x * blockDim.x;
  for (int i = blockIdx.x * blockDim.x + threadIdx.x; i < n4; i += stride) {
    float4 v = ((const float4*)x)[i];
    ushort_t h0 = f2bf(v.x), h1 = f2bf(v.y), h2 = f2bf(v.z), h3 = f2bf(v.w);
    ushort_t l0 = f2bf(v.x - bf2f(h0)), l1 = f2bf(v.y - bf2f(h1));
    ushort_t l2 = f2bf(v.z - bf2f(h2)), l3 = f2bf(v.w - bf2f(h3));
    uint2 hv, lv;
    hv.x = (uint_t)h0 | ((uint_t)h1 << 16); hv.y = (uint_t)h2 | ((uint_t)h3 << 16);
    lv.x = (uint_t)l0 | ((uint_t)l1 << 16); lv.y = (uint_t)l2 | ((uint_t)l3 << 16);
    ((uint2*)h)[i] = hv; ((uint2*)l)[i] = lv;
  }
}

// ---------------------------------------------------------------------------
// C[M,512] = act(A * W^T + bias).  3-MFMA bf16 split GEMM, 128x128, BK=32.
// (unchanged from R2 — verified correct)
// ---------------------------------------------------------------------------
template <bool ACT, bool SPLIT_OUT>
__global__ __launch_bounds__(256) void gemm_split(
    const ushort_t* __restrict__ Ah, const ushort_t* __restrict__ Al,
    const ushort_t* __restrict__ Bh, const ushort_t* __restrict__ Bl,
    const float* __restrict__ bias,
    ushort_t* __restrict__ Ch, ushort_t* __restrict__ Cl,
    float* __restrict__ Cf, int M) {
  __shared__ __align__(16) ushort_t lAh[128 * 32];
  __shared__ __align__(16) ushort_t lAl[128 * 32];
  __shared__ __align__(16) ushort_t lBh[128 * 32];
  __shared__ __align__(16) ushort_t lBl[128 * 32];

  const int t = threadIdx.x;
  const int m0 = blockIdx.x * 128;
  const int n0 = blockIdx.y * 128;
  const int w = t >> 6, lane = t & 63;
  const int wr = w >> 1, wc = w & 1;
  const int fl = lane & 15, kb = lane >> 4;

  f32x4 acc[4][4];
#pragma unroll
  for (int mi = 0; mi < 4; ++mi)
#pragma unroll
    for (int ni = 0; ni < 4; ++ni) acc[mi][ni] = (f32x4){0.f, 0.f, 0.f, 0.f};

  for (int kt = 0; kt < EMBED / 32; ++kt) {
#pragma unroll
    for (int j = 0; j < 2; ++j) {
      const int i = t + j * 256;
      const int r = i >> 2, p = i & 3;
      const int c = p ^ ((r >> 1) & 3);
      const size_t ga = (size_t)(m0 + r) * EMBED + kt * 32 + c * 8;
      const size_t gb = (size_t)(n0 + r) * EMBED + kt * 32 + c * 8;
      GLL(&Ah[ga], &lAh[(size_t)i * 8]);
      GLL(&Al[ga], &lAl[(size_t)i * 8]);
      GLL(&Bh[gb], &lBh[(size_t)i * 8]);
      GLL(&Bl[gb], &lBl[(size_t)i * 8]);
    }
    __syncthreads();

    bf16x8 fah[4], fal[4], fbh[4], fbl[4];
#pragma unroll
    for (int mi = 0; mi < 4; ++mi) {
      const int r = wr * 64 + mi * 16 + fl;
      const int p = kb ^ ((r >> 1) & 3);
      const int off = r * 32 + p * 8;
      fah[mi] = *(const bf16x8*)&lAh[off];
      fal[mi] = *(const bf16x8*)&lAl[off];
    }
#pragma unroll
    for (int ni = 0; ni < 4; ++ni) {
      const int r = wc * 64 + ni * 16 + fl;
      const int p = kb ^ ((r >> 1) & 3);
      const int off = r * 32 + p * 8;
      fbh[ni] = *(const bf16x8*)&lBh[off];
      fbl[ni] = *(const bf16x8*)&lBl[off];
    }
#pragma unroll
    for (int mi = 0; mi < 4; ++mi)
#pragma unroll
      for (int ni = 0; ni < 4; ++ni) {
        acc[mi][ni] = __builtin_amdgcn_mfma_f32_16x16x32_bf16(fah[mi], fbh[ni], acc[mi][ni], 0, 0, 0);
        acc[mi][ni] = __builtin_amdgcn_mfma_f32_16x16x32_bf16(fah[mi], fbl[ni], acc[mi][ni], 0, 0, 0);
        acc[mi][ni] = __builtin_amdgcn_mfma_f32_16x16x32_bf16(fal[mi], fbh[ni], acc[mi][ni], 0, 0, 0);
      }
    __syncthreads();
  }

  const int rq = lane >> 4;
#pragma unroll
  for (int mi = 0; mi < 4; ++mi)
#pragma unroll
    for (int ni = 0; ni < 4; ++ni) {
      const int col = n0 + wc * 64 + ni * 16 + fl;
      const float bv = bias[col];
#pragma unroll
      for (int q = 0; q < 4; ++q) {
        const int row = m0 + wr * 64 + mi * 16 + rq * 4 + q;
        float v = acc[mi][ni][q] + bv;
        if (ACT) v = (v > 0.f) ? (v + 1.f) : __expf(v);
        const size_t g = (size_t)row * EMBED + col;
        if (SPLIT_OUT) {
          const ushort_t hh = f2bf(v);
          Ch[g] = hh;
          Cl[g] = f2bf(v - bf2f(hh));
        } else {
          Cf[g] = v;
        }
      }
    }
}

// ---------------------------------------------------------------------------
// KV[nh][m][d] += sum_s V[s][m]*K[s][d];  Ksum[nh][d] += sum_s K[s][d]
// (unchanged from R2)
// ---------------------------------------------------------------------------
__global__ __launch_bounds__(256) void kv_kernel(
    const ushort_t* __restrict__ Kh, const ushort_t* __restrict__ Kl,
    const ushort_t* __restrict__ Vh, const ushort_t* __restrict__ Vl,
    float* __restrict__ KV, float* __restrict__ Ksum) {
  const int nh = blockIdx.x;
  const int n = nh >> 3, h = nh & 7;
  const int sbeg = blockIdx.y * 256;
  __shared__ float Ks[32][64];
  __shared__ float Vs[32][64];
  const int t = threadIdx.x;
  const int ty = t >> 4, tx = t & 15;
  float acc[4][4] = {};
  float ks[4] = {};

  for (int s0 = 0; s0 < 256; s0 += 32) {
#pragma unroll
    for (int i = 0; i < 2; ++i) {
      const int f = t + i * 256;
      const int r = f >> 4, cg = (f & 15) * 4;
      const size_t g = ((size_t)(n * SEQ + sbeg + s0 + r)) * EMBED + h * 64 + cg;
      uint2 kh = *(const uint2*)&Kh[g], kl = *(const uint2*)&Kl[g];
      uint2 vh = *(const uint2*)&Vh[g], vl = *(const uint2*)&Vl[g];
      Ks[r][cg + 0] = bflo(kh.x) + bflo(kl.x);
      Ks[r][cg + 1] = bfhi(kh.x) + bfhi(kl.x);
      Ks[r][cg + 2] = bflo(kh.y) + bflo(kl.y);
      Ks[r][cg + 3] = bfhi(kh.y) + bfhi(kl.y);
      Vs[r][cg + 0] = bflo(vh.x) + bflo(vl.x);
      Vs[r][cg + 1] = bfhi(vh.x) + bfhi(vl.x);
      Vs[r][cg + 2] = bflo(vh.y) + bflo(vl.y);
      Vs[r][cg + 3] = bfhi(vh.y) + bfhi(vl.y);
    }
    __syncthreads();
#pragma unroll 8
    for (int s = 0; s < 32; ++s) {
      float4 vv = *(float4*)&Vs[s][ty * 4];
      float4 kk = *(float4*)&Ks[s][tx * 4];
      float v4[4] = {vv.x, vv.y, vv.z, vv.w};
      float k4[4] = {kk.x, kk.y, kk.z, kk.w};
#pragma unroll
      for (int i = 0; i < 4; ++i)
#pragma unroll
        for (int j = 0; j < 4; ++j) acc[i][j] = fmaf(v4[i], k4[j], acc[i][j]);
      if (ty == 0) {
#pragma unroll
        for (int j = 0; j < 4; ++j) ks[j] += k4[j];
      }
    }
    __syncthreads();
  }
  float* kvb = &KV[(size_t)nh * 4096];
#pragma unroll
  for (int i = 0; i < 4; ++i)
#pragma unroll
    for (int j = 0; j < 4; ++j)
      atomicAdd(&kvb[(ty * 4 + i) * 64 + tx * 4 + j], acc[i][j]);
  if (ty == 0) {
#pragma unroll
    for (int j = 0; j < 4; ++j) atomicAdd(&Ksum[nh * 64 + tx * 4 + j], ks[j]);
  }
}

// ---------------------------------------------------------------------------
// B2[nh][80][64]: rows 0..63 = KV[nh][m][d]; row 64 = Ksum[nh][d]; 65..79 = 0.
// Split to bf16 hi/lo.
// ---------------------------------------------------------------------------
__global__ __launch_bounds__(256) void prep_b2(
    const float* __restrict__ KV, const float* __restrict__ Ksum,
    ushort_t* __restrict__ B2h, ushort_t* __restrict__ B2l) {
  const int nh = blockIdx.x;
  for (int idx = threadIdx.x; idx < 80 * 64; idx += 256) {
    const int r = idx >> 6, d = idx & 63;
    float val = 0.f;
    if (r < 64) val = KV[(size_t)nh * 4096 + r * 64 + d];
    else if (r == 64) val = Ksum[nh * 64 + d];
    const ushort_t hh = f2bf(val);
    B2h[(size_t)nh * 5120 + idx] = hh;
    B2l[(size_t)nh * 5120 + idx] = f2bf(val - bf2f(hh));
  }
}

// ---------------------------------------------------------------------------
// stage3 as MFMA GEMM: U[l, 0..79] = Qfeat[l,:] @ B2[nh]^T  (K=64).
// col 64 = dot(Q, Ksum) -> z. Vout[l, h*64+m] = U[l,m] / (U[l,64]+eps).
// 128 rows x 80 cols per block, 4 waves (32 rows each), 3-MFMA split.
// A staged via global_load_lds with swizzle p = c ^ (r&7) (2-way banks).
// ---------------------------------------------------------------------------
__global__ __launch_bounds__(256) void stage3_gemm(
    const ushort_t* __restrict__ Qh, const ushort_t* __restrict__ Ql,
    const ushort_t* __restrict__ B2h, const ushort_t* __restrict__ B2l,
    ushort_t* __restrict__ VoH, ushort_t* __restrict__ VoL) {
  __shared__ __align__(16) ushort_t lAh[128 * 64];
  __shared__ __align__(16) ushort_t lAl[128 * 64];
  const int t = threadIdx.x;
  const int nh = blockIdx.y;
  const int n = nh >> 3, h = nh & 7;
  const int l0 = blockIdx.x * 128;
  const int w = t >> 6, lane = t & 63;
  const int fl = lane & 15, kb = lane >> 4;

  // stage Q tile [128][64] hi/lo
#pragma unroll
  for (int j = 0; j < 4; ++j) {
    const int i = t + j * 256;          // 16B-chunk id, 0..1023
    const int r = i >> 3, p = i & 7;
    const int c = p ^ (r & 7);
    const size_t g = (size_t)(n * SEQ + l0 + r) * EMBED + h * 64 + c * 8;
    GLL(&Qh[g], &lAh[(size_t)i * 8]);
    GLL(&Ql[g], &lAl[(size_t)i * 8]);
  }

  // B2 fragments direct from global (L2-resident: 64 blocks share 20 KB)
  bf16x8 fbh[2][5], fbl[2][5];
#pragma unroll
  for (int ks = 0; ks < 2; ++ks)
#pragma unroll
    for (int ni = 0; ni < 5; ++ni) {
      const size_t g = (size_t)nh * 5120 + (ni * 16 + fl) * 64 + ks * 32 + kb * 8;
      fbh[ks][ni] = *(const bf16x8*)&B2h[g];
      fbl[ks][ni] = *(const bf16x8*)&B2l[g];
    }

  f32x4 acc[2][5];
#pragma unroll
  for (int mi = 0; mi < 2; ++mi)
#pragma unroll
    for (int ni = 0; ni < 5; ++ni) acc[mi][ni] = (f32x4){0.f, 0.f, 0.f, 0.f};

  __syncthreads();

#pragma unroll
  for (int ks = 0; ks < 2; ++ks) {
    bf16x8 fah[2], fal[2];
#pragma unroll
    for (int mi = 0; mi < 2; ++mi) {
      const int r = w * 32 + mi * 16 + fl;
      const int c = ks * 4 + kb;
      const int p = c ^ (r & 7);
      const int off = r * 64 + p * 8;
      fah[mi] = *(const bf16x8*)&lAh[off];
      fal[mi] = *(const bf16x8*)&lAl[off];
    }
#pragma unroll
    for (int mi = 0; mi < 2; ++mi)
#pragma unroll
      for (int ni = 0; ni < 5; ++ni) {
        acc[mi][ni] = __builtin_amdgcn_mfma_f32_16x16x32_bf16(fah[mi], fbh[ks][ni], acc[mi][ni], 0, 0, 0);
        acc[mi][ni] = __builtin_amdgcn_mfma_f32_16x16x32_bf16(fah[mi], fbl[ks][ni], acc[mi][ni], 0, 0, 0);
        acc[mi][ni] = __builtin_amdgcn_mfma_f32_16x16x32_bf16(fal[mi], fbh[ks][ni], acc[mi][ni], 0, 0, 0);
      }
  }

  // epilogue: den = col 64 (ni=4, fl=0), broadcast within each 16-lane group
  const int rq = lane >> 4;
#pragma unroll
  for (int mi = 0; mi < 2; ++mi) {
    float zin[4];
#pragma unroll
    for (int q = 0; q < 4; ++q) {
      const float den = __shfl(acc[mi][4][q], lane & 48);
      zin[q] = 1.f / (den + EPS);
    }
#pragma unroll
    for (int ni = 0; ni < 4; ++ni)
#pragma unroll
      for (int q = 0; q < 4; ++q) {
        const int row = l0 + w * 32 + mi * 16 + rq * 4 + q;
        const int col = h * 64 + ni * 16 + fl;
        const float v = acc[mi][ni][q] * zin[q];
        const size_t g = (size_t)(n * SEQ + row) * EMBED + col;
        const ushort_t hh = f2bf(v);
        VoH[g] = hh;
        VoL[g] = f2bf(v - bf2f(hh));
      }
  }
}

// ---------------------------------------------------------------------------
extern "C" void kernel_launch(void* const* d_in, const int* in_sizes, int n_in,
                              void* d_out, int out_size, void* d_ws,
                              size_t ws_size, hipStream_t stream) {
  const float* query = (const float*)d_in[0];
  const float* key   = (const float*)d_in[1];
  const float* value = (const float*)d_in[2];
  const float* Wq = (const float*)d_in[3];
  const float* bq = (const float*)d_in[4];
  const float* Wk = (const float*)d_in[5];
  const float* bk = (const float*)d_in[6];
  const float* Wv = (const float*)d_in[7];
  const float* bv = (const float*)d_in[8];
  const float* Wo = (const float*)d_in[9];
  const float* bo = (const float*)d_in[10];

  const int M = in_sizes[0] / EMBED;        // 65536
  const size_t ME = (size_t)M * EMBED;

  ushort_t* S1h = (ushort_t*)d_ws;  ushort_t* S1l = S1h + ME;
  ushort_t* S2h = S1h + 2 * ME;     ushort_t* S2l = S1h + 3 * ME;
  ushort_t* S3h = S1h + 4 * ME;     ushort_t* S3l = S1h + 5 * ME;
  float* KV   = (float*)(S1h + 6 * ME);
  float* Ksum = KV + 64 * 64 * 64;
  ushort_t* Wh = (ushort_t*)(Ksum + 64 * 64);
  ushort_t* Wl = Wh + (size_t)EMBED * EMBED;
  // B2 reuses the S1 slot (free after the Q projection consumes it)
  ushort_t* B2h = S1h;
  ushort_t* B2l = S1h + (size_t)64 * 5120;

  hipMemsetAsync(KV, 0, (64 * 64 * 64 + 64 * 64) * sizeof(float), stream);

  const int n4big = (int)(ME / 4);
  const int n4w = EMBED * EMBED / 4;
  dim3 gg(M / 128, EMBED / 128);

  // K = elu(key@Wk^T + bk)+1 -> S2
  convert_split<<<2048, 256, 0, stream>>>(key, S1h, S1l, n4big);
  convert_split<<<256, 256, 0, stream>>>(Wk, Wh, Wl, n4w);
  gemm_split<true, true><<<gg, 256, 0, stream>>>(S1h, S1l, Wh, Wl, bk, S2h, S2l, nullptr, M);

  // v = value@Wv^T + bv -> S3
  convert_split<<<2048, 256, 0, stream>>>(value, S1h, S1l, n4big);
  convert_split<<<256, 256, 0, stream>>>(Wv, Wh, Wl, n4w);
  gemm_split<false, true><<<gg, 256, 0, stream>>>(S1h, S1l, Wh, Wl, bv, S3h, S3l, nullptr, M);

  // KV, Ksum
  kv_kernel<<<dim3(64, 32), 256, 0, stream>>>(S2h, S2l, S3h, S3l, KV, Ksum);

  // Q = elu(query@Wq^T + bq)+1 -> S2
  convert_split<<<2048, 256, 0, stream>>>(query, S1h, S1l, n4big);
  convert_split<<<256, 256, 0, stream>>>(Wq, Wh, Wl, n4w);
  gemm_split<true, true><<<gg, 256, 0, stream>>>(S1h, S1l, Wh, Wl, bq, S2h, S2l, nullptr, M);

  // stage3 via MFMA: prep B2 (into S1, now free), then GEMM -> S3
  prep_b2<<<64, 256, 0, stream>>>(KV, Ksum, B2h, B2l);
  stage3_gemm<<<dim3(SEQ / 128, 64), 256, 0, stream>>>(S2h, S2l, B2h, B2l, S3h, S3l);

  // out = Vout@Wo^T + bo
  convert_split<<<256, 256, 0, stream>>>(Wo, Wh, Wl, n4w);
  gemm_split<false, false><<<gg, 256, 0, stream>>>(S3h, S3l, Wh, Wl, bo, nullptr, nullptr, (float*)d_out, M);
}

// Round 4
// 1105.079 us; speedup vs baseline: 2.0597x; 1.1041x over previous
//
#include <hip/hip_runtime.h>
#include <math.h>

#define EMBED 512
#define SEQ   8192
#define EPS   1e-6f

typedef __attribute__((ext_vector_type(8))) short bf16x8;
typedef __attribute__((ext_vector_type(4))) float f32x4;
typedef unsigned short ushort_t;
typedef unsigned int uint_t;

__device__ __forceinline__ ushort_t f2bf(float x) {  // RNE float->bf16
  uint_t b = __float_as_uint(x);
  b += 0x7fff + ((b >> 16) & 1);
  return (ushort_t)(b >> 16);
}
__device__ __forceinline__ float bf2f(ushort_t u) {
  return __uint_as_float(((uint_t)u) << 16);
}

// split 8 fp32 -> bf16 hi/lo vectors (x ~= hi + lo, err <= 2^-18 |x|)
__device__ __forceinline__ void split8(const float* av, bf16x8& hv, bf16x8& lv) {
#pragma unroll
  for (int e = 0; e < 8; ++e) {
    const ushort_t hh = f2bf(av[e]);
    hv[e] = (short)hh;
    lv[e] = (short)f2bf(av[e] - bf2f(hh));
  }
}

#define GLL(srcp, dstp)                                                       \
  __builtin_amdgcn_global_load_lds(                                           \
      (const __attribute__((address_space(1))) void*)(const void*)(srcp),     \
      (__attribute__((address_space(3))) void*)(void*)(dstp), 16, 0, 0)

// ---------------------------------------------------------------------------
// fp32 -> bf16 hi/lo split (only used for the 1 MB weight matrices now)
// ---------------------------------------------------------------------------
__global__ void convert_split(const float* __restrict__ x,
                              ushort_t* __restrict__ h,
                              ushort_t* __restrict__ l, int n4) {
  const int stride = gridDim.x * blockDim.x;
  for (int i = blockIdx.x * blockDim.x + threadIdx.x; i < n4; i += stride) {
    float4 v = ((const float4*)x)[i];
    ushort_t h0 = f2bf(v.x), h1 = f2bf(v.y), h2 = f2bf(v.z), h3 = f2bf(v.w);
    ushort_t l0 = f2bf(v.x - bf2f(h0)), l1 = f2bf(v.y - bf2f(h1));
    ushort_t l2 = f2bf(v.z - bf2f(h2)), l3 = f2bf(v.w - bf2f(h3));
    uint2 hv, lv;
    hv.x = (uint_t)h0 | ((uint_t)h1 << 16); hv.y = (uint_t)h2 | ((uint_t)h3 << 16);
    lv.x = (uint_t)l0 | ((uint_t)l1 << 16); lv.y = (uint_t)l2 | ((uint_t)l3 << 16);
    ((uint2*)h)[i] = hv; ((uint2*)l)[i] = lv;
  }
}

// ---------------------------------------------------------------------------
// C[M,512] = act(A * W^T + bias), A fp32 (split in-kernel), W pre-split hi/lo.
// 128x128 tile, BK=32, 4 waves 2x2, 3-MFMA split per frag pair.
// A: reg-staged (fp32 load -> split8 -> swizzled ds_write_b128).
// B: global_load_lds(16B) with source-side swizzle. Swizzle p = c ^ ((r>>1)&3).
// grid: x = n-block (4, fast) so A-tile reuse hits L2; y = m-block.
// ---------------------------------------------------------------------------
template <bool ACT>
__global__ __launch_bounds__(256) void gemm_f32A(
    const float* __restrict__ A, const ushort_t* __restrict__ Bh,
    const ushort_t* __restrict__ Bl, const float* __restrict__ bias,
    float* __restrict__ C, int M) {
  __shared__ __align__(16) ushort_t lAh[128 * 32];
  __shared__ __align__(16) ushort_t lAl[128 * 32];
  __shared__ __align__(16) ushort_t lBh[128 * 32];
  __shared__ __align__(16) ushort_t lBl[128 * 32];

  const int t = threadIdx.x;
  const int n0 = blockIdx.x * 128;
  const int m0 = blockIdx.y * 128;
  const int w = t >> 6, lane = t & 63;
  const int wr = w >> 1, wc = w & 1;
  const int fl = lane & 15, kb = lane >> 4;

  f32x4 acc[4][4];
#pragma unroll
  for (int mi = 0; mi < 4; ++mi)
#pragma unroll
    for (int ni = 0; ni < 4; ++ni) acc[mi][ni] = (f32x4){0.f, 0.f, 0.f, 0.f};

  for (int kt = 0; kt < EMBED / 32; ++kt) {
    // B: async global->LDS (pre-split weights), source-swizzled
#pragma unroll
    for (int j = 0; j < 2; ++j) {
      const int i = t + j * 256;
      const int r = i >> 2, p = i & 3;
      const int c = p ^ ((r >> 1) & 3);
      const size_t gb = (size_t)(n0 + r) * EMBED + kt * 32 + c * 8;
      GLL(&Bh[gb], &lBh[(size_t)i * 8]);
      GLL(&Bl[gb], &lBl[(size_t)i * 8]);
    }
    // A: fp32 load -> split -> swizzled ds_write
#pragma unroll
    for (int j = 0; j < 2; ++j) {
      const int i = t + j * 256;
      const int r = i >> 2, c8 = i & 3;
      const float* ap = &A[(size_t)(m0 + r) * EMBED + kt * 32 + c8 * 8];
      float av[8];
      *(float4*)&av[0] = *(const float4*)ap;
      *(float4*)&av[4] = *(const float4*)(ap + 4);
      bf16x8 hv, lv;
      split8(av, hv, lv);
      const int p = c8 ^ ((r >> 1) & 3);
      const int off = r * 32 + p * 8;
      *(bf16x8*)&lAh[off] = hv;
      *(bf16x8*)&lAl[off] = lv;
    }
    __syncthreads();

    bf16x8 fah[4], fal[4], fbh[4], fbl[4];
#pragma unroll
    for (int mi = 0; mi < 4; ++mi) {
      const int r = wr * 64 + mi * 16 + fl;
      const int p = kb ^ ((r >> 1) & 3);
      const int off = r * 32 + p * 8;
      fah[mi] = *(const bf16x8*)&lAh[off];
      fal[mi] = *(const bf16x8*)&lAl[off];
    }
#pragma unroll
    for (int ni = 0; ni < 4; ++ni) {
      const int r = wc * 64 + ni * 16 + fl;
      const int p = kb ^ ((r >> 1) & 3);
      const int off = r * 32 + p * 8;
      fbh[ni] = *(const bf16x8*)&lBh[off];
      fbl[ni] = *(const bf16x8*)&lBl[off];
    }
#pragma unroll
    for (int mi = 0; mi < 4; ++mi)
#pragma unroll
      for (int ni = 0; ni < 4; ++ni) {
        acc[mi][ni] = __builtin_amdgcn_mfma_f32_16x16x32_bf16(fah[mi], fbh[ni], acc[mi][ni], 0, 0, 0);
        acc[mi][ni] = __builtin_amdgcn_mfma_f32_16x16x32_bf16(fah[mi], fbl[ni], acc[mi][ni], 0, 0, 0);
        acc[mi][ni] = __builtin_amdgcn_mfma_f32_16x16x32_bf16(fal[mi], fbh[ni], acc[mi][ni], 0, 0, 0);
      }
    __syncthreads();
  }

  // epilogue: C/D layout col = lane&15, row = (lane>>4)*4 + reg
  const int rq = lane >> 4;
#pragma unroll
  for (int mi = 0; mi < 4; ++mi)
#pragma unroll
    for (int ni = 0; ni < 4; ++ni) {
      const int col = n0 + wc * 64 + ni * 16 + fl;
      const float bv = bias[col];
#pragma unroll
      for (int q = 0; q < 4; ++q) {
        const int row = m0 + wr * 64 + mi * 16 + rq * 4 + q;
        float v = acc[mi][ni][q] + bv;
        if (ACT) v = (v > 0.f) ? (v + 1.f) : __expf(v);
        C[(size_t)row * EMBED + col] = v;
      }
    }
}

// ---------------------------------------------------------------------------
// KV[nh][m][d] += sum_s V[s][m]*K[s][d];  Ksum[nh][d] += sum_s K[s][d]
// fp32 inputs, GLL staging, double-buffered 2-phase (T3-min).
// grid (64 nh, 32 s-chunks), 256 thr; split-K atomics.
// ---------------------------------------------------------------------------
__global__ __launch_bounds__(256) void kv_f32(
    const float* __restrict__ Kf, const float* __restrict__ Vf,
    float* __restrict__ KV, float* __restrict__ Ksum) {
  const int nh = blockIdx.x;
  const int n = nh >> 3, h = nh & 7;
  const int sbeg = blockIdx.y * 256;
  __shared__ __align__(16) float Ks[2][32][64];
  __shared__ __align__(16) float Vs[2][32][64];
  const int t = threadIdx.x;
  const int ty = t >> 4, tx = t & 15;
  float acc[4][4] = {};
  float ks[4] = {};

  // prologue stage chunk 0 into buf 0
#pragma unroll
  for (int j = 0; j < 2; ++j) {
    const int i = t + j * 256;
    const int r = i >> 4, c4 = (i & 15) * 4;
    const size_t g = ((size_t)(n * SEQ + sbeg + r)) * EMBED + h * 64 + c4;
    GLL(&Kf[g], &Ks[0][r][c4]);
    GLL(&Vf[g], &Vs[0][r][c4]);
  }
  __syncthreads();

  int buf = 0;
  for (int c = 0; c < 8; ++c) {
    if (c < 7) {  // stage next chunk into other buffer (overlaps compute)
#pragma unroll
      for (int j = 0; j < 2; ++j) {
        const int i = t + j * 256;
        const int r = i >> 4, c4 = (i & 15) * 4;
        const size_t g =
            ((size_t)(n * SEQ + sbeg + (c + 1) * 32 + r)) * EMBED + h * 64 + c4;
        GLL(&Kf[g], &Ks[buf ^ 1][r][c4]);
        GLL(&Vf[g], &Vs[buf ^ 1][r][c4]);
      }
    }
#pragma unroll 8
    for (int s = 0; s < 32; ++s) {
      float4 vv = *(float4*)&Vs[buf][s][ty * 4];
      float4 kk = *(float4*)&Ks[buf][s][tx * 4];
      float v4[4] = {vv.x, vv.y, vv.z, vv.w};
      float k4[4] = {kk.x, kk.y, kk.z, kk.w};
#pragma unroll
      for (int i = 0; i < 4; ++i)
#pragma unroll
        for (int j = 0; j < 4; ++j) acc[i][j] = fmaf(v4[i], k4[j], acc[i][j]);
      if (ty == 0) {
#pragma unroll
        for (int j = 0; j < 4; ++j) ks[j] += k4[j];
      }
    }
    __syncthreads();  // drains vmcnt (next chunk landed) + protects buf reuse
    buf ^= 1;
  }

  float* kvb = &KV[(size_t)nh * 4096];
#pragma unroll
  for (int i = 0; i < 4; ++i)
#pragma unroll
    for (int j = 0; j < 4; ++j)
      atomicAdd(&kvb[(ty * 4 + i) * 64 + tx * 4 + j], acc[i][j]);
  if (ty == 0) {
#pragma unroll
    for (int j = 0; j < 4; ++j) atomicAdd(&Ksum[nh * 64 + tx * 4 + j], ks[j]);
  }
}

// ---------------------------------------------------------------------------
// B2[nh][80][64]: rows 0..63 = KV[m][d]; row 64 = Ksum[d]; 65..79 = 0. hi/lo.
// ---------------------------------------------------------------------------
__global__ __launch_bounds__(256) void prep_b2(
    const float* __restrict__ KV, const float* __restrict__ Ksum,
    ushort_t* __restrict__ B2h, ushort_t* __restrict__ B2l) {
  const int nh = blockIdx.x;
  for (int idx = threadIdx.x; idx < 80 * 64; idx += 256) {
    const int r = idx >> 6, d = idx & 63;
    float val = 0.f;
    if (r < 64) val = KV[(size_t)nh * 4096 + r * 64 + d];
    else if (r == 64) val = Ksum[nh * 64 + d];
    const ushort_t hh = f2bf(val);
    B2h[(size_t)nh * 5120 + idx] = hh;
    B2l[(size_t)nh * 5120 + idx] = f2bf(val - bf2f(hh));
  }
}

// ---------------------------------------------------------------------------
// stage3: U[l,0..79] = Q[l,:] @ B2[nh]^T (K=64); Vout = U[:,m]/(U[:,64]+eps).
// Q fp32 reg-staged+split; swizzle p = c ^ (r&7). Vout fp32.
// grid (64 nh fast, 64 l-blocks) so 8 head-blocks share Q rows in L2.
// ---------------------------------------------------------------------------
__global__ __launch_bounds__(256) void stage3_f32A(
    const float* __restrict__ Qf, const ushort_t* __restrict__ B2h,
    const ushort_t* __restrict__ B2l, float* __restrict__ Vo) {
  __shared__ __align__(16) ushort_t lAh[128 * 64];
  __shared__ __align__(16) ushort_t lAl[128 * 64];
  const int t = threadIdx.x;
  const int nh = blockIdx.x;
  const int n = nh >> 3, h = nh & 7;
  const int l0 = blockIdx.y * 128;
  const int w = t >> 6, lane = t & 63;
  const int fl = lane & 15, kb = lane >> 4;

  // stage Q tile [128][64]: fp32 -> split -> swizzled ds_write
#pragma unroll
  for (int j = 0; j < 4; ++j) {
    const int i = t + j * 256;
    const int r = i >> 3, c8 = i & 7;
    const float* qp = &Qf[(size_t)(n * SEQ + l0 + r) * EMBED + h * 64 + c8 * 8];
    float av[8];
    *(float4*)&av[0] = *(const float4*)qp;
    *(float4*)&av[4] = *(const float4*)(qp + 4);
    bf16x8 hv, lv;
    split8(av, hv, lv);
    const int p = c8 ^ (r & 7);
    const int off = r * 64 + p * 8;
    *(bf16x8*)&lAh[off] = hv;
    *(bf16x8*)&lAl[off] = lv;
  }

  // B2 fragments direct from global (L2-resident)
  bf16x8 fbh[2][5], fbl[2][5];
#pragma unroll
  for (int ks = 0; ks < 2; ++ks)
#pragma unroll
    for (int ni = 0; ni < 5; ++ni) {
      const size_t g = (size_t)nh * 5120 + (ni * 16 + fl) * 64 + ks * 32 + kb * 8;
      fbh[ks][ni] = *(const bf16x8*)&B2h[g];
      fbl[ks][ni] = *(const bf16x8*)&B2l[g];
    }

  f32x4 acc[2][5];
#pragma unroll
  for (int mi = 0; mi < 2; ++mi)
#pragma unroll
    for (int ni = 0; ni < 5; ++ni) acc[mi][ni] = (f32x4){0.f, 0.f, 0.f, 0.f};

  __syncthreads();

#pragma unroll
  for (int ks = 0; ks < 2; ++ks) {
    bf16x8 fah[2], fal[2];
#pragma unroll
    for (int mi = 0; mi < 2; ++mi) {
      const int r = w * 32 + mi * 16 + fl;
      const int c = ks * 4 + kb;
      const int p = c ^ (r & 7);
      const int off = r * 64 + p * 8;
      fah[mi] = *(const bf16x8*)&lAh[off];
      fal[mi] = *(const bf16x8*)&lAl[off];
    }
#pragma unroll
    for (int mi = 0; mi < 2; ++mi)
#pragma unroll
      for (int ni = 0; ni < 5; ++ni) {
        acc[mi][ni] = __builtin_amdgcn_mfma_f32_16x16x32_bf16(fah[mi], fbh[ks][ni], acc[mi][ni], 0, 0, 0);
        acc[mi][ni] = __builtin_amdgcn_mfma_f32_16x16x32_bf16(fah[mi], fbl[ks][ni], acc[mi][ni], 0, 0, 0);
        acc[mi][ni] = __builtin_amdgcn_mfma_f32_16x16x32_bf16(fal[mi], fbh[ks][ni], acc[mi][ni], 0, 0, 0);
      }
  }

  const int rq = lane >> 4;
#pragma unroll
  for (int mi = 0; mi < 2; ++mi) {
    float zin[4];
#pragma unroll
    for (int q = 0; q < 4; ++q) {
      const float den = __shfl(acc[mi][4][q], lane & 48);
      zin[q] = 1.f / (den + EPS);
    }
#pragma unroll
    for (int ni = 0; ni < 4; ++ni)
#pragma unroll
      for (int q = 0; q < 4; ++q) {
        const int row = l0 + w * 32 + mi * 16 + rq * 4 + q;
        const int col = h * 64 + ni * 16 + fl;
        Vo[(size_t)(n * SEQ + row) * EMBED + col] = acc[mi][ni][q] * zin[q];
      }
  }
}

// ---------------------------------------------------------------------------
extern "C" void kernel_launch(void* const* d_in, const int* in_sizes, int n_in,
                              void* d_out, int out_size, void* d_ws,
                              size_t ws_size, hipStream_t stream) {
  const float* query = (const float*)d_in[0];
  const float* key   = (const float*)d_in[1];
  const float* value = (const float*)d_in[2];
  const float* Wq = (const float*)d_in[3];
  const float* bq = (const float*)d_in[4];
  const float* Wk = (const float*)d_in[5];
  const float* bk = (const float*)d_in[6];
  const float* Wv = (const float*)d_in[7];
  const float* bv = (const float*)d_in[8];
  const float* Wo = (const float*)d_in[9];
  const float* bo = (const float*)d_in[10];

  const int M = in_sizes[0] / EMBED;        // 65536
  const size_t ME = (size_t)M * EMBED;

  // ws: two fp32 [M][512] slots + KV + Ksum + W hi/lo + B2 hi/lo
  float* S1 = (float*)d_ws;                 // K-proj, later Q-proj
  float* S2 = S1 + ME;                      // v-proj, later Vout
  float* KV = S2 + ME;                      // 64*64*64
  float* Ksum = KV + 64 * 64 * 64;          // 64*64
  ushort_t* Wh = (ushort_t*)(Ksum + 64 * 64);
  ushort_t* Wl = Wh + (size_t)EMBED * EMBED;
  ushort_t* B2h = Wl + (size_t)EMBED * EMBED;
  ushort_t* B2l = B2h + (size_t)64 * 5120;

  hipMemsetAsync(KV, 0, (64 * 64 * 64 + 64 * 64) * sizeof(float), stream);

  const int n4w = EMBED * EMBED / 4;
  dim3 gg(EMBED / 128, M / 128);  // x = n-block (fast) for A-tile L2 reuse

  // K = elu(key@Wk^T + bk)+1 -> S1
  convert_split<<<256, 256, 0, stream>>>(Wk, Wh, Wl, n4w);
  gemm_f32A<true><<<gg, 256, 0, stream>>>(key, Wh, Wl, bk, S1, M);

  // v = value@Wv^T + bv -> S2
  convert_split<<<256, 256, 0, stream>>>(Wv, Wh, Wl, n4w);
  gemm_f32A<false><<<gg, 256, 0, stream>>>(value, Wh, Wl, bv, S2, M);

  // KV, Ksum
  kv_f32<<<dim3(64, 32), 256, 0, stream>>>(S1, S2, KV, Ksum);

  // Q = elu(query@Wq^T + bq)+1 -> S1 (K dead after kv)
  convert_split<<<256, 256, 0, stream>>>(Wq, Wh, Wl, n4w);
  gemm_f32A<true><<<gg, 256, 0, stream>>>(query, Wh, Wl, bq, S1, M);

  // stage3 -> S2 (v dead after kv)
  prep_b2<<<64, 256, 0, stream>>>(KV, Ksum, B2h, B2l);
  stage3_f32A<<<dim3(64, SEQ / 128), 256, 0, stream>>>(S1, B2h, B2l, S2);

  // out = Vout@Wo^T + bo
  convert_split<<<256, 256, 0, stream>>>(Wo, Wh, Wl, n4w);
  gemm_f32A<false><<<gg, 256, 0, stream>>>(S2, Wh, Wl, bo, (float*)d_out, M);
}